// Round 11
// baseline (365.787 us; speedup 1.0000x reference)
//
#include <hip/hip_runtime.h>
#include <hip/hip_bf16.h>
#include <stdint.h>

// ---------------------------------------------------------------------------
// RandomFeatureAttention: B=4, N=4096, E=1024, H=16, D=64, P_DIM=64, feat=128
// Round 18: dispatch-count reduction (9 -> 6), hot kernels untouched.
//  - detect_kernel deleted: cvt_all computes the dtype flag inline per-block
//    (2 loads + 6 shfl) and block 0 publishes *flag for downstream kernels.
//  - cvt_x + cvt4 merged into one cvt_all dispatch (10240 blocks).
//  - kv_reduce fused into o_kernel (float4 slab-sum into sKVT; same order,
//    bit-identical); gKV buffer removed.
// gemm2 / gemm1m2 / kv inner loops identical to the 358.7 us session best.
// ---------------------------------------------------------------------------

typedef __bf16 bf16x8 __attribute__((ext_vector_type(8)));
typedef float f32x4 __attribute__((ext_vector_type(4)));
typedef unsigned short u16x4 __attribute__((ext_vector_type(4)));

#define AS1 __attribute__((address_space(1)))
#define AS3 __attribute__((address_space(3)))

__device__ __forceinline__ void gl2lds16(const void* g, void* l) {
    __builtin_amdgcn_global_load_lds((const AS1 void*)g, (AS3 void*)l, 16, 0, 0);
}

static constexpr int GM = 16384, GN = 1024, GK = 1024;
static constexpr int KV_SLABS = 8;

// --------------------- inline dtype detection (wave-level) ------------------
// Replicates the old detect_kernel: scan x[0..127] (as ushort), count bf16-
// plausible exponents, threshold 100/128. Every wave computes the same value.
__device__ __forceinline__ int detect_bf16(const unsigned short* x) {
    const int lane = threadIdx.x & 63;
    int cnt = 0;
#pragma unroll
    for (int i = 0; i < 2; ++i) {
        const unsigned short u = x[i * 64 + lane];
        const int e = (u >> 7) & 0xFF;
        cnt += (e >= 117 && e <= 131) ? 1 : 0;
    }
    cnt += __shfl_xor(cnt, 1, 64);
    cnt += __shfl_xor(cnt, 2, 64);
    cnt += __shfl_xor(cnt, 4, 64);
    cnt += __shfl_xor(cnt, 8, 64);
    cnt += __shfl_xor(cnt, 16, 64);
    cnt += __shfl_xor(cnt, 32, 64);
    return cnt >= 100;
}

// ----------------------------- convert -------------------------------------
__device__ __forceinline__ void cvt8(const float* s, __hip_bfloat16* d) {
    const float4 a = *(const float4*)s;
    const float4 b = *(const float4*)(s + 4);
    union { uint4 u; __hip_bfloat16 h[8]; } pk;
    pk.h[0] = __float2bfloat16(a.x); pk.h[1] = __float2bfloat16(a.y);
    pk.h[2] = __float2bfloat16(a.z); pk.h[3] = __float2bfloat16(a.w);
    pk.h[4] = __float2bfloat16(b.x); pk.h[5] = __float2bfloat16(b.y);
    pk.h[6] = __float2bfloat16(b.z); pk.h[7] = __float2bfloat16(b.w);
    *(uint4*)d = pk.u;
}

// one dispatch: x (8192 blocks) + 4 weight matrices (512 blocks each).
// Also publishes the dtype flag (block 0) for downstream kernels.
__global__ __launch_bounds__(256) void cvt_all_kernel(
    const void* __restrict__ x,  __hip_bfloat16* __restrict__ xb,
    const void* __restrict__ s0, __hip_bfloat16* __restrict__ d0,
    const void* __restrict__ s1, __hip_bfloat16* __restrict__ d1,
    const void* __restrict__ s2, __hip_bfloat16* __restrict__ d2,
    const void* __restrict__ s3, __hip_bfloat16* __restrict__ d3,
    int* __restrict__ flag) {
    const int fl = detect_bf16((const unsigned short*)x);
    if (blockIdx.x == 0 && threadIdx.x == 0) *flag = fl;
    if (fl) return;
    if (blockIdx.x < 8192) {
        const int i = (blockIdx.x * 256 + threadIdx.x) * 8;   // XE = 16Mi
        cvt8((const float*)x + i, xb + i);
    } else {
        const int bb    = blockIdx.x - 8192;
        const int which = bb >> 9;
        const int i = ((bb & 511) * 256 + threadIdx.x) * 8;   // WE = 1Mi
        const float* s = (const float*)(which == 0 ? s0 : which == 1 ? s1
                                       : which == 2 ? s2 : s3) + i;
        __hip_bfloat16* d = (which == 0 ? d0 : which == 1 ? d1
                             : which == 2 ? d2 : d3) + i;
        cvt8(s, d);
    }
}

// --------------------- dual-M single-W GEMM (Q, final) ---------------------
// Block computes 256x128 (two 128x128 M-tiles sharing the W tile).
// Grid 512, XCD-pinned: xcd owns mpairs [xcd*8, xcd*8+8) (A slab 4MB = L2).
__global__ __launch_bounds__(256, 2) void gemm1m2_kernel(
    const void* __restrict__ Adirect,
    const __hip_bfloat16* __restrict__ Acvt,
    const void* __restrict__ Wr, const __hip_bfloat16* __restrict__ Wc,
    const void* __restrict__ bias_raw,
    void* __restrict__ Cout,
    const int* __restrict__ flag, int last)
{
    __shared__ unsigned short smem[3 * 128 * 64];  // sA0 | sA1 | sB
    unsigned short* sA0 = smem;
    unsigned short* sA1 = smem + 128 * 64;
    unsigned short* sB  = smem + 2 * 128 * 64;

    const int tid  = threadIdx.x;
    const int lane = tid & 63;
    const int w    = tid >> 6;
    const int wm   = w >> 1, wn = w & 1;
    const int lr   = lane & 15, lk = lane >> 4;

    const int id   = blockIdx.x;
    const int xcd  = id & 7;
    const int s    = id >> 3;
    const int m0   = (xcd * 8 + (s & 7)) * 256;
    const int n0   = (s >> 3) * 128;
    const int fl   = *flag;

    const __hip_bfloat16* A = fl ? (const __hip_bfloat16*)Adirect : Acvt;
    const __hip_bfloat16* W = fl ? (const __hip_bfloat16*)Wr : Wc;

    f32x4 acc[2][4][4];
#pragma unroll
    for (int t = 0; t < 2; ++t)
#pragma unroll
        for (int i = 0; i < 4; ++i)
#pragma unroll
            for (int j = 0; j < 4; ++j)
                acc[t][i][j] = (f32x4){0.f, 0.f, 0.f, 0.f};

    const __hip_bfloat16* Ab0 = A + (size_t)m0 * GK;
    const __hip_bfloat16* Ab1 = A + (size_t)(m0 + 128) * GK;
    const __hip_bfloat16* Wb  = W + (size_t)n0 * GK;

    for (int k0 = 0; k0 < GK; k0 += 64) {
#pragma unroll
        for (int j = 0; j < 4; ++j) {
            const int chunk = j * 256 + tid;
            const int row   = chunk >> 3;
            const int c     = chunk & 7;
            const int cs    = c ^ (row & 7);
            const size_t go = (size_t)row * GK + k0 + cs * 8;
            const int lo = (j * 256 + w * 64) * 16;
            gl2lds16(Ab0 + go, (char*)sA0 + lo);
            gl2lds16(Ab1 + go, (char*)sA1 + lo);
            gl2lds16(Wb  + go, (char*)sB  + lo);
        }
        __syncthreads();
#pragma unroll
        for (int kk = 0; kk < 64; kk += 32) {
            const int jj = ((kk >> 3) + lk) ^ (lr & 7);
            bf16x8 a0f[4], a1f[4], bfr[4];
#pragma unroll
            for (int i = 0; i < 4; ++i)
                a0f[i] = *(const bf16x8*)&sA0[(wm * 64 + i * 16 + lr) * 64 + jj * 8];
#pragma unroll
            for (int i = 0; i < 4; ++i)
                a1f[i] = *(const bf16x8*)&sA1[(wm * 64 + i * 16 + lr) * 64 + jj * 8];
#pragma unroll
            for (int j = 0; j < 4; ++j)
                bfr[j] = *(const bf16x8*)&sB[(wn * 64 + j * 16 + lr) * 64 + jj * 8];
#pragma unroll
            for (int i = 0; i < 4; ++i)
#pragma unroll
                for (int j = 0; j < 4; ++j) {
                    acc[0][i][j] = __builtin_amdgcn_mfma_f32_16x16x32_bf16(
                        a0f[i], bfr[j], acc[0][i][j], 0, 0, 0);
                    acc[1][i][j] = __builtin_amdgcn_mfma_f32_16x16x32_bf16(
                        a1f[i], bfr[j], acc[1][i][j], 0, 0, 0);
                }
        }
        __syncthreads();
    }

    const bool f32out = (last != 0) && (fl == 0);
    if (f32out) {
#pragma unroll
        for (int t = 0; t < 2; ++t)
#pragma unroll
            for (int j = 0; j < 4; ++j) {
                const int col = n0 + wn * 64 + j * 16 + lr;
                const float bv = ((const float*)bias_raw)[col];
#pragma unroll
                for (int i = 0; i < 4; ++i) {
                    const int rbase = m0 + t * 128 + wm * 64 + i * 16 + lk * 4;
#pragma unroll
                    for (int r = 0; r < 4; ++r)
                        ((float*)Cout)[(size_t)(rbase + r) * GN + col] = acc[t][i][j][r] + bv;
                }
            }
        return;
    }
    __hip_bfloat16* sC = (__hip_bfloat16*)smem;
#pragma unroll
    for (int t = 0; t < 2; ++t) {
#pragma unroll
        for (int j = 0; j < 4; ++j) {
            const int col = wn * 64 + j * 16 + lr;
            const float bv = fl ? __bfloat162float(((const __hip_bfloat16*)bias_raw)[n0 + col])
                                : ((const float*)bias_raw)[n0 + col];
            const int c2 = col >> 3, o = col & 7;
#pragma unroll
            for (int i = 0; i < 4; ++i) {
                const int rb = wm * 64 + i * 16 + lk * 4;
#pragma unroll
                for (int r = 0; r < 4; ++r) {
                    const int row = rb + r;
                    sC[row * 128 + (c2 ^ (row & 7)) * 8 + o] =
                        __float2bfloat16(acc[t][i][j][r] + bv);
                }
            }
        }
        __syncthreads();
        {
            const int row = tid >> 1, hf = tid & 1;
            __hip_bfloat16* dst = (__hip_bfloat16*)Cout +
                (size_t)(m0 + t * 128 + row) * GN + n0 + hf * 64;
#pragma unroll
            for (int q = 0; q < 8; ++q) {
                const int cc = (hf * 8 + q) ^ (row & 7);
                *(uint4*)(dst + q * 8) = *(const uint4*)&sC[row * 128 + cc * 8];
            }
        }
        __syncthreads();
    }
}

// ------------------------- 2-output GEMM (K,V) -----------------------------
__global__ __launch_bounds__(256, 2) void gemm2_kernel(
    const void* __restrict__ Adirect,
    const __hip_bfloat16* __restrict__ Acvt,
    const void* __restrict__ W0r, const __hip_bfloat16* __restrict__ W0c,
    const void* __restrict__ W1r, const __hip_bfloat16* __restrict__ W1c,
    const void* __restrict__ b0r, const void* __restrict__ b1r,
    void* __restrict__ o0, void* __restrict__ o1,
    const int* __restrict__ flag)
{
    __shared__ unsigned short smem[3 * 128 * 64];  // sA | sB0 | sB1
    unsigned short* sA  = smem;
    unsigned short* sB0 = smem + 128 * 64;
    unsigned short* sB1 = smem + 2 * 128 * 64;

    const int tid  = threadIdx.x;
    const int lane = tid & 63;
    const int w    = tid >> 6;
    const int wm   = w >> 1, wn = w & 1;
    const int lr   = lane & 15, lk = lane >> 4;

    const int id    = blockIdx.x;
    const int xcd   = id & 7;
    const int slot  = id >> 3;
    const int m0    = (xcd * 16 + (slot & 15)) * 128;
    const int n0    = (slot >> 4) * 128;
    const int fl    = *flag;

    const __hip_bfloat16* A  = fl ? (const __hip_bfloat16*)Adirect : Acvt;
    const __hip_bfloat16* W0 = fl ? (const __hip_bfloat16*)W0r : W0c;
    const __hip_bfloat16* W1 = fl ? (const __hip_bfloat16*)W1r : W1c;

    f32x4 acc[2][4][4];
#pragma unroll
    for (int t = 0; t < 2; ++t)
#pragma unroll
        for (int i = 0; i < 4; ++i)
#pragma unroll
            for (int j = 0; j < 4; ++j)
                acc[t][i][j] = (f32x4){0.f, 0.f, 0.f, 0.f};

    const __hip_bfloat16* Ab  = A + (size_t)m0 * GK;
    const __hip_bfloat16* W0b = W0 + (size_t)n0 * GK;
    const __hip_bfloat16* W1b = W1 + (size_t)n0 * GK;

    for (int k0 = 0; k0 < GK; k0 += 64) {
#pragma unroll
        for (int j = 0; j < 4; ++j) {
            const int chunk = j * 256 + tid;
            const int row   = chunk >> 3;
            const int c     = chunk & 7;
            const int cs    = c ^ (row & 7);
            const size_t go = (size_t)row * GK + k0 + cs * 8;
            const int lo = (j * 256 + w * 64) * 16;
            gl2lds16(Ab  + go, (char*)sA  + lo);
            gl2lds16(W0b + go, (char*)sB0 + lo);
            gl2lds16(W1b + go, (char*)sB1 + lo);
        }
        __syncthreads();
#pragma unroll
        for (int kk = 0; kk < 64; kk += 32) {
            const int jj = ((kk >> 3) + lk) ^ (lr & 7);
            bf16x8 af[4], b0f[4], b1f[4];
#pragma unroll
            for (int i = 0; i < 4; ++i)
                af[i] = *(const bf16x8*)&sA[(wm * 64 + i * 16 + lr) * 64 + jj * 8];
#pragma unroll
            for (int j = 0; j < 4; ++j)
                b0f[j] = *(const bf16x8*)&sB0[(wn * 64 + j * 16 + lr) * 64 + jj * 8];
#pragma unroll
            for (int j = 0; j < 4; ++j)
                b1f[j] = *(const bf16x8*)&sB1[(wn * 64 + j * 16 + lr) * 64 + jj * 8];
#pragma unroll
            for (int i = 0; i < 4; ++i)
#pragma unroll
                for (int j = 0; j < 4; ++j) {
                    acc[0][i][j] = __builtin_amdgcn_mfma_f32_16x16x32_bf16(
                        af[i], b0f[j], acc[0][i][j], 0, 0, 0);
                    acc[1][i][j] = __builtin_amdgcn_mfma_f32_16x16x32_bf16(
                        af[i], b1f[j], acc[1][i][j], 0, 0, 0);
                }
        }
        __syncthreads();
    }

    __hip_bfloat16* sC = (__hip_bfloat16*)smem;
#pragma unroll
    for (int t = 0; t < 2; ++t) {
        const void* bias_raw = t ? b1r : b0r;
        void* Cout = t ? o1 : o0;
#pragma unroll
        for (int j = 0; j < 4; ++j) {
            const int col = wn * 64 + j * 16 + lr;
            const float bv = fl ? __bfloat162float(((const __hip_bfloat16*)bias_raw)[n0 + col])
                                : ((const float*)bias_raw)[n0 + col];
            const int c2 = col >> 3, o = col & 7;
#pragma unroll
            for (int i = 0; i < 4; ++i) {
                const int rb = wm * 64 + i * 16 + lk * 4;
#pragma unroll
                for (int r = 0; r < 4; ++r) {
                    const int row = rb + r;
                    sC[row * 128 + (c2 ^ (row & 7)) * 8 + o] =
                        __float2bfloat16(acc[t][i][j][r] + bv);
                }
            }
        }
        __syncthreads();
        {
            const int row = tid >> 1, hf = tid & 1;
            __hip_bfloat16* dst = (__hip_bfloat16*)Cout + (size_t)(m0 + row) * GN + n0 + hf * 64;
#pragma unroll
            for (int q = 0; q < 8; ++q) {
                const int cc = (hf * 8 + q) ^ (row & 7);
                *(uint4*)(dst + q * 8) = *(const uint4*)&sC[row * 128 + cc * 8];
            }
        }
        __syncthreads();
    }
}

// ----------------------------- shared helpers -------------------------------
__device__ __forceinline__ void load_P(const void* Praw, int f,
                                       __hip_bfloat16* sP, int tid) {
    const int e = tid >> 2, q = tid & 3;
    union { uint4 u[2]; __hip_bfloat16 h[16]; } pk;
    if (f) {
        pk.u[0] = *(const uint4*)((const __hip_bfloat16*)Praw + e * 64 + q * 16);
        pk.u[1] = *(const uint4*)((const __hip_bfloat16*)Praw + e * 64 + q * 16 + 8);
    } else {
        const float* ps = (const float*)Praw + e * 64 + q * 16;
#pragma unroll
        for (int j = 0; j < 16; ++j) pk.h[j] = __float2bfloat16(ps[j]);
    }
    *(uint4*)&sP[e * 72 + q * 16]     = pk.u[0];
    *(uint4*)&sP[e * 72 + q * 16 + 8] = pk.u[1];
}

__device__ __forceinline__ float sumsq16(uint4 a, uint4 b) {
    union { uint4 u; __hip_bfloat16 h[8]; } x0, x1;
    x0.u = a; x1.u = b;
    float ss = 0.f;
#pragma unroll
    for (int j = 0; j < 8; ++j) {
        float v0 = __bfloat162float(x0.h[j]); ss += v0 * v0;
        float v1 = __bfloat162float(x1.h[j]); ss += v1 * v1;
    }
    return ss;
}

// pack sin/cos of 4 values into two u16x4 (bf16 bits), scaled by 0.125
__device__ __forceinline__ void sincos4_pack(const f32x4& pa, const float* rn,
                                             u16x4& s4, u16x4& c4) {
#pragma unroll
    for (int r = 0; r < 4; ++r) {
        float sv, cv;
        __sincosf(pa[r] * rn[r], &sv, &cv);
        __hip_bfloat16 hs = __float2bfloat16(sv * 0.125f);
        __hip_bfloat16 hc = __float2bfloat16(cv * 0.125f);
        s4[r] = *(unsigned short*)&hs;
        c4[r] = *(unsigned short*)&hc;
    }
}

// ----------------------------- kv kernel -----------------------------------
// grid (8, 64): 512 tokens per block, 8 iters. Partial kv -> private slab
// (plain stores, no atomics). Slab layout: PKV[(slab*64 + bh)*8192 + e*64+d].
__global__ __launch_bounds__(256) void kv_kernel(
    const __hip_bfloat16* __restrict__ Km,
    const __hip_bfloat16* __restrict__ Vm,
    const void* __restrict__ Praw,
    float* __restrict__ PKV,
    const int* __restrict__ flag)
{
    __shared__ __hip_bfloat16 sK[64 * 72];     // [n][d] (wave-local rows)
    __shared__ __hip_bfloat16 sVT[64 * 72];    // [d][n] (cross-wave)
    __shared__ __hip_bfloat16 sP[64 * 72];     // [e][d] (read-only)
    __shared__ __hip_bfloat16 sKFT[128 * 72];  // [e][n] (cross-wave)
    __shared__ float sRN[64];

    const int tid  = threadIdx.x;
    const int lane = tid & 63;
    const int w    = tid >> 6;
    const int lr   = lane & 15, lk = lane >> 4;
    const int bh   = blockIdx.y;
    const int b    = bh >> 4, h = bh & 15;
    const int nst  = blockIdx.x * 512;
    const int f    = *flag;
    const int n    = tid >> 2, q2 = tid & 3;

    load_P(Praw, f, sP, tid);

    f32x4 acck[2][4];
#pragma unroll
    for (int i = 0; i < 2; ++i)
#pragma unroll
        for (int j = 0; j < 4; ++j)
            acck[i][j] = (f32x4){0.f, 0.f, 0.f, 0.f};

    size_t base = ((size_t)(b * 4096 + nst + n)) * 1024 + h * 64 + q2 * 16;
    uint4 ka = *(const uint4*)(Km + base), kb = *(const uint4*)(Km + base + 8);
    uint4 va = *(const uint4*)(Vm + base), vb = *(const uint4*)(Vm + base + 8);

    for (int s = 0; s < 8; ++s) {
        __syncthreads();  // prev kv-MFMA done with sVT/sKFT (s==0: sP visible)
        *(uint4*)&sK[n * 72 + q2 * 16]     = ka;
        *(uint4*)&sK[n * 72 + q2 * 16 + 8] = kb;
        {
            union { uint4 u[2]; __hip_bfloat16 h[16]; } vv;
            vv.u[0] = va; vv.u[1] = vb;
#pragma unroll
            for (int j = 0; j < 16; ++j) sVT[(q2 * 16 + j) * 72 + n] = vv.h[j];
        }
        {
            float ss = sumsq16(ka, kb);
            ss += __shfl_xor(ss, 1, 64);
            ss += __shfl_xor(ss, 2, 64);
            if (q2 == 0) sRN[n] = 2.0f / (sqrtf(ss) + 1e-4f);  // H^0.25 = 2
        }
        if (s < 7) {
            base = ((size_t)(b * 4096 + nst + (s + 1) * 64 + n)) * 1024 + h * 64 + q2 * 16;
            ka = *(const uint4*)(Km + base); kb = *(const uint4*)(Km + base + 8);
            va = *(const uint4*)(Vm + base); vb = *(const uint4*)(Vm + base + 8);
        }
        // proj (wave-local) + sincos -> sKFT (packed b64 stores)
        {
            bf16x8 afr0 = *(const bf16x8*)&sK[(w * 16 + lr) * 72 + lk * 8];
            bf16x8 afr1 = *(const bf16x8*)&sK[(w * 16 + lr) * 72 + 32 + lk * 8];
            float rn[4];
#pragma unroll
            for (int r = 0; r < 4; ++r) rn[r] = sRN[w * 16 + lk * 4 + r];
            const int rb = w * 16 + lk * 4;
#pragma unroll
            for (int eb = 0; eb < 4; ++eb) {
                f32x4 pa = (f32x4){0.f, 0.f, 0.f, 0.f};
                bf16x8 b0 = *(const bf16x8*)&sP[(eb * 16 + lr) * 72 + lk * 8];
                bf16x8 b1 = *(const bf16x8*)&sP[(eb * 16 + lr) * 72 + 32 + lk * 8];
                pa = __builtin_amdgcn_mfma_f32_16x16x32_bf16(afr0, b0, pa, 0, 0, 0);
                pa = __builtin_amdgcn_mfma_f32_16x16x32_bf16(afr1, b1, pa, 0, 0, 0);
                const int col = eb * 16 + lr;
                u16x4 s4, c4;
                sincos4_pack(pa, rn, s4, c4);
                *(u16x4*)&sKFT[col * 72 + rb]        = s4;
                *(u16x4*)&sKFT[(col + 64) * 72 + rb] = c4;
            }
        }
        __syncthreads();  // sKFT + sVT complete across waves
#pragma unroll
        for (int ks = 0; ks < 2; ++ks) {
            bf16x8 a2[2], b2[4];
            a2[0] = *(const bf16x8*)&sKFT[(w * 16 + lr) * 72 + ks * 32 + lk * 8];
            a2[1] = *(const bf16x8*)&sKFT[((w + 4) * 16 + lr) * 72 + ks * 32 + lk * 8];
#pragma unroll
            for (int db = 0; db < 4; ++db)
                b2[db] = *(const bf16x8*)&sVT[(db * 16 + lr) * 72 + ks * 32 + lk * 8];
#pragma unroll
            for (int i = 0; i < 2; ++i)
#pragma unroll
                for (int db = 0; db < 4; ++db)
                    acck[i][db] = __builtin_amdgcn_mfma_f32_16x16x32_bf16(
                        a2[i], b2[db], acck[i][db], 0, 0, 0);
        }
    }

    float* out = PKV + ((size_t)blockIdx.x * 64 + bh) * 8192;
#pragma unroll
    for (int i = 0; i < 2; ++i)
#pragma unroll
        for (int db = 0; db < 4; ++db)
#pragma unroll
            for (int r = 0; r < 4; ++r) {
                const int e = (w + 4 * i) * 16 + lk * 4 + r;
                const int d = db * 16 + lr;
                out[e * 64 + d] = acck[i][db][r];
            }
}

// ----------------------------- o kernel ------------------------------------
// Fuses the old kv_reduce: each block sums its head's 8 PKV slabs (float4)
// directly into sKVT. proj MFMA operands swapped (A=P, B=Q) for packed
// feature stores; rn is one scalar per token.
__global__ __launch_bounds__(256) void o_kernel(
    const __hip_bfloat16* __restrict__ Qm,
    const void* __restrict__ Praw,
    const float* __restrict__ PKV,
    __hip_bfloat16* __restrict__ O,
    const int* __restrict__ flag)
{
    __shared__ __hip_bfloat16 sQ[64 * 72];     // [n][d] wave-local rows
    __shared__ __hip_bfloat16 sP[64 * 72];     // read-only
    __shared__ __hip_bfloat16 sQF[64 * 136];   // [n][e] wave-local rows
    __shared__ __hip_bfloat16 sKVT[64 * 136];  // [d][e] read-only
    __shared__ float sRN[64];

    const int tid  = threadIdx.x;
    const int lane = tid & 63;
    const int w    = tid >> 6;
    const int lr   = lane & 15, lk = lane >> 4;
    const int bh   = blockIdx.y;
    const int b    = bh >> 4, h = bh & 15;
    const int nst  = blockIdx.x * 256;
    const int f    = *flag;
    const int n    = tid >> 2, q2 = tid & 3;

    load_P(Praw, f, sP, tid);
    {
        // fused slab reduction: gKV[t] = sum_sl PKV[sl][bh][t]
        const float* kvb = PKV + (size_t)bh * 8192;
#pragma unroll 1
        for (int t4 = tid * 4; t4 < 8192; t4 += 1024) {
            f32x4 sacc = (f32x4){0.f, 0.f, 0.f, 0.f};
#pragma unroll
            for (int sl = 0; sl < KV_SLABS; ++sl) {
                const float4 v = *(const float4*)(kvb + (size_t)sl * 64 * 8192 + t4);
                sacc[0] += v.x; sacc[1] += v.y; sacc[2] += v.z; sacc[3] += v.w;
            }
#pragma unroll
            for (int j = 0; j < 4; ++j) {
                const int t = t4 + j;
                sKVT[(t & 63) * 136 + (t >> 6)] = __float2bfloat16(sacc[j]);
            }
        }
    }

    size_t base = ((size_t)(b * 4096 + nst + n)) * 1024 + h * 64 + q2 * 16;
    uint4 qa = *(const uint4*)(Qm + base), qb = *(const uint4*)(Qm + base + 8);

    __syncthreads();  // sP + sKVT visible to all waves

    for (int s = 0; s < 4; ++s) {
        const int gn0 = nst + s * 64;
        *(uint4*)&sQ[n * 72 + q2 * 16]     = qa;
        *(uint4*)&sQ[n * 72 + q2 * 16 + 8] = qb;
        {
            float ss = sumsq16(qa, qb);
            ss += __shfl_xor(ss, 1, 64);
            ss += __shfl_xor(ss, 2, 64);
            if (q2 == 0) sRN[n] = 2.0f / (sqrtf(ss) + 1e-4f);
        }
        if (s < 3) {
            base = ((size_t)(b * 4096 + nst + (s + 1) * 64 + n)) * 1024 + h * 64 + q2 * 16;
            qa = *(const uint4*)(Qm + base); qb = *(const uint4*)(Qm + base + 8);
        }
        // proj (flipped: A = P, B = Q) + sincos -> sQF packed
        {
            bf16x8 qf0 = *(const bf16x8*)&sQ[(w * 16 + lr) * 72 + lk * 8];
            bf16x8 qf1 = *(const bf16x8*)&sQ[(w * 16 + lr) * 72 + 32 + lk * 8];
            const int tok = w * 16 + lr;          // wave-local row of sQ/sRN
            const float rnv = sRN[tok];
            float rn[4] = {rnv, rnv, rnv, rnv};
#pragma unroll
            for (int eb = 0; eb < 4; ++eb) {
                f32x4 pa = (f32x4){0.f, 0.f, 0.f, 0.f};
                bf16x8 p0 = *(const bf16x8*)&sP[(eb * 16 + lr) * 72 + lk * 8];
                bf16x8 p1 = *(const bf16x8*)&sP[(eb * 16 + lr) * 72 + 32 + lk * 8];
                pa = __builtin_amdgcn_mfma_f32_16x16x32_bf16(p0, qf0, pa, 0, 0, 0);
                pa = __builtin_amdgcn_mfma_f32_16x16x32_bf16(p1, qf1, pa, 0, 0, 0);
                // lane holds token 'tok', e = eb*16 + lk*4 + r (consecutive)
                const int e0 = eb * 16 + lk * 4;
                u16x4 s4, c4;
                sincos4_pack(pa, rn, s4, c4);
                *(u16x4*)&sQF[tok * 136 + e0]      = s4;
                *(u16x4*)&sQF[tok * 136 + 64 + e0] = c4;
            }
        }
        f32x4 oacc[4];
#pragma unroll
        for (int nb = 0; nb < 4; ++nb) oacc[nb] = (f32x4){0.f, 0.f, 0.f, 0.f};
#pragma unroll
        for (int ks = 0; ks < 4; ++ks) {
            bf16x8 aa = *(const bf16x8*)&sQF[(w * 16 + lr) * 136 + ks * 32 + lk * 8];
#pragma unroll
            for (int nb = 0; nb < 4; ++nb) {
                bf16x8 bb = *(const bf16x8*)&sKVT[(nb * 16 + lr) * 136 + ks * 32 + lk * 8];
                oacc[nb] = __builtin_amdgcn_mfma_f32_16x16x32_bf16(aa, bb, oacc[nb], 0, 0, 0);
            }
        }
#pragma unroll
        for (int nb = 0; nb < 4; ++nb)
#pragma unroll
            for (int r = 0; r < 4; ++r)
                sQ[(w * 16 + lk * 4 + r) * 72 + nb * 16 + lr] =
                    __float2bfloat16(oacc[nb][r]);
        {
            uint4 o0 = *(uint4*)&sQ[n * 72 + q2 * 16];
            uint4 o1 = *(uint4*)&sQ[n * 72 + q2 * 16 + 8];
            const size_t obase = ((size_t)(b * 4096 + gn0 + n)) * 1024 + h * 64 + q2 * 16;
            *(uint4*)(O + obase)     = o0;
            *(uint4*)(O + obase + 8) = o1;
        }
    }
}

// ----------------------------- launcher ------------------------------------
extern "C" void kernel_launch(void* const* d_in, const int* in_sizes, int n_in,
                              void* d_out, int out_size, void* d_ws, size_t ws_size,
                              hipStream_t stream)
{
    (void)in_sizes; (void)n_in; (void)out_size; (void)ws_size;
    const void* x  = d_in[0];
    const void* Wq = d_in[1];
    const void* bq = d_in[2];
    const void* Wk = d_in[3];
    const void* bk = d_in[4];
    const void* Wv = d_in[5];
    const void* bv = d_in[6];
    const void* Wo = d_in[7];
    const void* bo = d_in[8];
    const void* P  = d_in[9];

    constexpr size_t XE = (size_t)GM * GN;
    constexpr size_t WE = (size_t)GN * GK;

    __hip_bfloat16* xb  = (__hip_bfloat16*)d_ws;
    __hip_bfloat16* wqb = xb + XE;
    __hip_bfloat16* wkb = wqb + WE;
    __hip_bfloat16* wvb = wkb + WE;
    __hip_bfloat16* wob = wvb + WE;
    __hip_bfloat16* R1  = wob + WE;          // K, later O
    __hip_bfloat16* R2  = R1 + XE;           // V, later Q
    float* PKV = (float*)(R2 + XE);          // 8 slabs x 64 x 8192
    int* flag  = (int*)(PKV + (size_t)KV_SLABS * 64 * 8192);

    dim3 blk(256);
    // one dispatch: detect + all conversions
    hipLaunchKernelGGL(cvt_all_kernel, dim3(10240), blk, 0, stream,
                       x, xb, Wq, wqb, Wk, wkb, Wv, wvb, Wo, wob, flag);

    // K, V (2-out, shared A)
    hipLaunchKernelGGL(gemm2_kernel, dim3(1024), blk, 0, stream,
                       x, xb, Wk, wkb, Wv, wvb, bk, bv, R1, R2, flag);
    hipLaunchKernelGGL(kv_kernel, dim3(KV_SLABS, 64), blk, 0, stream, R1, R2, P, PKV, flag);
    // Q (V dead -> R2), dual-M
    hipLaunchKernelGGL(gemm1m2_kernel, dim3(512), blk, 0, stream,
                       x, xb, Wq, wqb, bq, R2, flag, 0);
    // o: fused slab-reduce + feature map + PV
    hipLaunchKernelGGL(o_kernel, dim3(16, 64), blk, 0, stream, R2, P, PKV, R1, flag);
    // out = O@Wo^T + bo, dual-M
    hipLaunchKernelGGL(gemm1m2_kernel, dim3(512), blk, 0, stream,
                       R1, R1, Wo, wob, bo, d_out, flag, 1);
}

// Round 12
// 351.783 us; speedup vs baseline: 1.0398x; 1.0398x over previous
//
#include <hip/hip_runtime.h>
#include <hip/hip_bf16.h>
#include <stdint.h>

// ---------------------------------------------------------------------------
// RandomFeatureAttention: B=4, N=4096, E=1024, H=16, D=64, P_DIM=64, feat=128
// Round 19: base = exact round-16 source (358.7 us session best). Single
// isolated change: kv parallelism doubled — KV_SLABS 8->16, grid (16,64),
// 4 serial iters/block instead of 8 (halves the barrier+prefetch chain).
// reduce sums 16 slabs. Everything else byte-identical.
// ---------------------------------------------------------------------------

typedef __bf16 bf16x8 __attribute__((ext_vector_type(8)));
typedef float f32x4 __attribute__((ext_vector_type(4)));

#define AS1 __attribute__((address_space(1)))
#define AS3 __attribute__((address_space(3)))

__device__ __forceinline__ void gl2lds16(const void* g, void* l) {
    __builtin_amdgcn_global_load_lds((const AS1 void*)g, (AS3 void*)l, 16, 0, 0);
}

static constexpr int GM = 16384, GN = 1024, GK = 1024;
static constexpr int KV_SLABS = 16;

// ----------------------------- dtype detect --------------------------------
__global__ void detect_kernel(const unsigned short* __restrict__ x,
                              int* __restrict__ flag) {
    __shared__ int s;
    const int lane = threadIdx.x;  // 64 threads
    if (lane == 0) s = 0;
    __syncthreads();
    int cnt = 0;
#pragma unroll
    for (int i = 0; i < 2; ++i) {
        const unsigned short u = x[i * 64 + lane];
        const int e = (u >> 7) & 0xFF;
        cnt += (e >= 117 && e <= 131) ? 1 : 0;
    }
    atomicAdd(&s, cnt);
    __syncthreads();
    if (lane == 0) *flag = (s >= 100) ? 1 : 0;  // 1 = bf16 storage
}

// ----------------------------- convert -------------------------------------
__device__ __forceinline__ void cvt8(const float* s, __hip_bfloat16* d) {
    const float4 a = *(const float4*)s;
    const float4 b = *(const float4*)(s + 4);
    union { uint4 u; __hip_bfloat16 h[8]; } pk;
    pk.h[0] = __float2bfloat16(a.x); pk.h[1] = __float2bfloat16(a.y);
    pk.h[2] = __float2bfloat16(a.z); pk.h[3] = __float2bfloat16(a.w);
    pk.h[4] = __float2bfloat16(b.x); pk.h[5] = __float2bfloat16(b.y);
    pk.h[6] = __float2bfloat16(b.z); pk.h[7] = __float2bfloat16(b.w);
    *(uint4*)d = pk.u;
}

__global__ __launch_bounds__(256) void cvt_kernel(
    const void* __restrict__ src, __hip_bfloat16* __restrict__ dst,
    int n, const int* __restrict__ flag) {
    if (*flag) return;
    const int i = (blockIdx.x * 256 + threadIdx.x) * 8;
    if (i >= n) return;
    cvt8((const float*)src + i, dst + i);
}

// one dispatch converts all 4 weight matrices (512 blocks each)
__global__ __launch_bounds__(256) void cvt4_kernel(
    const void* __restrict__ s0, __hip_bfloat16* __restrict__ d0,
    const void* __restrict__ s1, __hip_bfloat16* __restrict__ d1,
    const void* __restrict__ s2, __hip_bfloat16* __restrict__ d2,
    const void* __restrict__ s3, __hip_bfloat16* __restrict__ d3,
    const int* __restrict__ flag) {
    if (*flag) return;
    const int which = blockIdx.x >> 9;
    const int i = ((blockIdx.x & 511) * 256 + threadIdx.x) * 8;  // WE = 1 Mi
    const float* s = (const float*)(which == 0 ? s0 : which == 1 ? s1
                                   : which == 2 ? s2 : s3) + i;
    __hip_bfloat16* d = (which == 0 ? d0 : which == 1 ? d1
                         : which == 2 ? d2 : d3) + i;
    cvt8(s, d);
}

// --------------------- dual-M single-W GEMM (Q, final) ---------------------
// Block computes 256x128 (two 128x128 M-tiles sharing the W tile).
// Grid 512, XCD-pinned: xcd owns mpairs [xcd*8, xcd*8+8) (A slab 4MB = L2).
__global__ __launch_bounds__(256, 2) void gemm1m2_kernel(
    const void* __restrict__ Adirect,
    const __hip_bfloat16* __restrict__ Acvt,
    const void* __restrict__ Wr, const __hip_bfloat16* __restrict__ Wc,
    const void* __restrict__ bias_raw,
    void* __restrict__ Cout,
    const int* __restrict__ flag, int last)
{
    __shared__ unsigned short smem[3 * 128 * 64];  // sA0 | sA1 | sB
    unsigned short* sA0 = smem;
    unsigned short* sA1 = smem + 128 * 64;
    unsigned short* sB  = smem + 2 * 128 * 64;

    const int tid  = threadIdx.x;
    const int lane = tid & 63;
    const int w    = tid >> 6;
    const int wm   = w >> 1, wn = w & 1;
    const int lr   = lane & 15, lk = lane >> 4;

    const int id   = blockIdx.x;
    const int xcd  = id & 7;
    const int s    = id >> 3;
    const int m0   = (xcd * 8 + (s & 7)) * 256;
    const int n0   = (s >> 3) * 128;
    const int fl   = *flag;

    const __hip_bfloat16* A = fl ? (const __hip_bfloat16*)Adirect : Acvt;
    const __hip_bfloat16* W = fl ? (const __hip_bfloat16*)Wr : Wc;

    f32x4 acc[2][4][4];
#pragma unroll
    for (int t = 0; t < 2; ++t)
#pragma unroll
        for (int i = 0; i < 4; ++i)
#pragma unroll
            for (int j = 0; j < 4; ++j)
                acc[t][i][j] = (f32x4){0.f, 0.f, 0.f, 0.f};

    const __hip_bfloat16* Ab0 = A + (size_t)m0 * GK;
    const __hip_bfloat16* Ab1 = A + (size_t)(m0 + 128) * GK;
    const __hip_bfloat16* Wb  = W + (size_t)n0 * GK;

    for (int k0 = 0; k0 < GK; k0 += 64) {
#pragma unroll
        for (int j = 0; j < 4; ++j) {
            const int chunk = j * 256 + tid;
            const int row   = chunk >> 3;
            const int c     = chunk & 7;
            const int cs    = c ^ (row & 7);
            const size_t go = (size_t)row * GK + k0 + cs * 8;
            const int lo = (j * 256 + w * 64) * 16;
            gl2lds16(Ab0 + go, (char*)sA0 + lo);
            gl2lds16(Ab1 + go, (char*)sA1 + lo);
            gl2lds16(Wb  + go, (char*)sB  + lo);
        }
        __syncthreads();
#pragma unroll
        for (int kk = 0; kk < 64; kk += 32) {
            const int jj = ((kk >> 3) + lk) ^ (lr & 7);
            bf16x8 a0f[4], a1f[4], bfr[4];
#pragma unroll
            for (int i = 0; i < 4; ++i)
                a0f[i] = *(const bf16x8*)&sA0[(wm * 64 + i * 16 + lr) * 64 + jj * 8];
#pragma unroll
            for (int i = 0; i < 4; ++i)
                a1f[i] = *(const bf16x8*)&sA1[(wm * 64 + i * 16 + lr) * 64 + jj * 8];
#pragma unroll
            for (int j = 0; j < 4; ++j)
                bfr[j] = *(const bf16x8*)&sB[(wn * 64 + j * 16 + lr) * 64 + jj * 8];
#pragma unroll
            for (int i = 0; i < 4; ++i)
#pragma unroll
                for (int j = 0; j < 4; ++j) {
                    acc[0][i][j] = __builtin_amdgcn_mfma_f32_16x16x32_bf16(
                        a0f[i], bfr[j], acc[0][i][j], 0, 0, 0);
                    acc[1][i][j] = __builtin_amdgcn_mfma_f32_16x16x32_bf16(
                        a1f[i], bfr[j], acc[1][i][j], 0, 0, 0);
                }
        }
        __syncthreads();
    }

    const bool f32out = (last != 0) && (fl == 0);
    if (f32out) {
#pragma unroll
        for (int t = 0; t < 2; ++t)
#pragma unroll
            for (int j = 0; j < 4; ++j) {
                const int col = n0 + wn * 64 + j * 16 + lr;
                const float bv = ((const float*)bias_raw)[col];
#pragma unroll
                for (int i = 0; i < 4; ++i) {
                    const int rbase = m0 + t * 128 + wm * 64 + i * 16 + lk * 4;
#pragma unroll
                    for (int r = 0; r < 4; ++r)
                        ((float*)Cout)[(size_t)(rbase + r) * GN + col] = acc[t][i][j][r] + bv;
                }
            }
        return;
    }
    __hip_bfloat16* sC = (__hip_bfloat16*)smem;
#pragma unroll
    for (int t = 0; t < 2; ++t) {
#pragma unroll
        for (int j = 0; j < 4; ++j) {
            const int col = wn * 64 + j * 16 + lr;
            const float bv = fl ? __bfloat162float(((const __hip_bfloat16*)bias_raw)[n0 + col])
                                : ((const float*)bias_raw)[n0 + col];
            const int c2 = col >> 3, o = col & 7;
#pragma unroll
            for (int i = 0; i < 4; ++i) {
                const int rb = wm * 64 + i * 16 + lk * 4;
#pragma unroll
                for (int r = 0; r < 4; ++r) {
                    const int row = rb + r;
                    sC[row * 128 + (c2 ^ (row & 7)) * 8 + o] =
                        __float2bfloat16(acc[t][i][j][r] + bv);
                }
            }
        }
        __syncthreads();
        {
            const int row = tid >> 1, hf = tid & 1;
            __hip_bfloat16* dst = (__hip_bfloat16*)Cout +
                (size_t)(m0 + t * 128 + row) * GN + n0 + hf * 64;
#pragma unroll
            for (int q = 0; q < 8; ++q) {
                const int cc = (hf * 8 + q) ^ (row & 7);
                *(uint4*)(dst + q * 8) = *(const uint4*)&sC[row * 128 + cc * 8];
            }
        }
        __syncthreads();
    }
}

// ------------------------- 2-output GEMM (K,V) -----------------------------
__global__ __launch_bounds__(256, 2) void gemm2_kernel(
    const void* __restrict__ Adirect,
    const __hip_bfloat16* __restrict__ Acvt,
    const void* __restrict__ W0r, const __hip_bfloat16* __restrict__ W0c,
    const void* __restrict__ W1r, const __hip_bfloat16* __restrict__ W1c,
    const void* __restrict__ b0r, const void* __restrict__ b1r,
    void* __restrict__ o0, void* __restrict__ o1,
    const int* __restrict__ flag)
{
    __shared__ unsigned short smem[3 * 128 * 64];  // sA | sB0 | sB1
    unsigned short* sA  = smem;
    unsigned short* sB0 = smem + 128 * 64;
    unsigned short* sB1 = smem + 2 * 128 * 64;

    const int tid  = threadIdx.x;
    const int lane = tid & 63;
    const int w    = tid >> 6;
    const int wm   = w >> 1, wn = w & 1;
    const int lr   = lane & 15, lk = lane >> 4;

    const int id    = blockIdx.x;
    const int xcd   = id & 7;
    const int slot  = id >> 3;
    const int m0    = (xcd * 16 + (slot & 15)) * 128;
    const int n0    = (slot >> 4) * 128;
    const int fl    = *flag;

    const __hip_bfloat16* A  = fl ? (const __hip_bfloat16*)Adirect : Acvt;
    const __hip_bfloat16* W0 = fl ? (const __hip_bfloat16*)W0r : W0c;
    const __hip_bfloat16* W1 = fl ? (const __hip_bfloat16*)W1r : W1c;

    f32x4 acc[2][4][4];
#pragma unroll
    for (int t = 0; t < 2; ++t)
#pragma unroll
        for (int i = 0; i < 4; ++i)
#pragma unroll
            for (int j = 0; j < 4; ++j)
                acc[t][i][j] = (f32x4){0.f, 0.f, 0.f, 0.f};

    const __hip_bfloat16* Ab  = A + (size_t)m0 * GK;
    const __hip_bfloat16* W0b = W0 + (size_t)n0 * GK;
    const __hip_bfloat16* W1b = W1 + (size_t)n0 * GK;

    for (int k0 = 0; k0 < GK; k0 += 64) {
#pragma unroll
        for (int j = 0; j < 4; ++j) {
            const int chunk = j * 256 + tid;
            const int row   = chunk >> 3;
            const int c     = chunk & 7;
            const int cs    = c ^ (row & 7);
            const size_t go = (size_t)row * GK + k0 + cs * 8;
            const int lo = (j * 256 + w * 64) * 16;
            gl2lds16(Ab  + go, (char*)sA  + lo);
            gl2lds16(W0b + go, (char*)sB0 + lo);
            gl2lds16(W1b + go, (char*)sB1 + lo);
        }
        __syncthreads();
#pragma unroll
        for (int kk = 0; kk < 64; kk += 32) {
            const int jj = ((kk >> 3) + lk) ^ (lr & 7);
            bf16x8 af[4], b0f[4], b1f[4];
#pragma unroll
            for (int i = 0; i < 4; ++i)
                af[i] = *(const bf16x8*)&sA[(wm * 64 + i * 16 + lr) * 64 + jj * 8];
#pragma unroll
            for (int j = 0; j < 4; ++j)
                b0f[j] = *(const bf16x8*)&sB0[(wn * 64 + j * 16 + lr) * 64 + jj * 8];
#pragma unroll
            for (int j = 0; j < 4; ++j)
                b1f[j] = *(const bf16x8*)&sB1[(wn * 64 + j * 16 + lr) * 64 + jj * 8];
#pragma unroll
            for (int i = 0; i < 4; ++i)
#pragma unroll
                for (int j = 0; j < 4; ++j) {
                    acc[0][i][j] = __builtin_amdgcn_mfma_f32_16x16x32_bf16(
                        af[i], b0f[j], acc[0][i][j], 0, 0, 0);
                    acc[1][i][j] = __builtin_amdgcn_mfma_f32_16x16x32_bf16(
                        af[i], b1f[j], acc[1][i][j], 0, 0, 0);
                }
        }
        __syncthreads();
    }

    __hip_bfloat16* sC = (__hip_bfloat16*)smem;
#pragma unroll
    for (int t = 0; t < 2; ++t) {
        const void* bias_raw = t ? b1r : b0r;
        void* Cout = t ? o1 : o0;
#pragma unroll
        for (int j = 0; j < 4; ++j) {
            const int col = wn * 64 + j * 16 + lr;
            const float bv = fl ? __bfloat162float(((const __hip_bfloat16*)bias_raw)[n0 + col])
                                : ((const float*)bias_raw)[n0 + col];
            const int c2 = col >> 3, o = col & 7;
#pragma unroll
            for (int i = 0; i < 4; ++i) {
                const int rb = wm * 64 + i * 16 + lk * 4;
#pragma unroll
                for (int r = 0; r < 4; ++r) {
                    const int row = rb + r;
                    sC[row * 128 + (c2 ^ (row & 7)) * 8 + o] =
                        __float2bfloat16(acc[t][i][j][r] + bv);
                }
            }
        }
        __syncthreads();
        {
            const int row = tid >> 1, hf = tid & 1;
            __hip_bfloat16* dst = (__hip_bfloat16*)Cout + (size_t)(m0 + row) * GN + n0 + hf * 64;
#pragma unroll
            for (int q = 0; q < 8; ++q) {
                const int cc = (hf * 8 + q) ^ (row & 7);
                *(uint4*)(dst + q * 8) = *(const uint4*)&sC[row * 128 + cc * 8];
            }
        }
        __syncthreads();
    }
}

// ----------------------------- shared helpers -------------------------------
__device__ __forceinline__ void load_P(const void* Praw, int f,
                                       __hip_bfloat16* sP, int tid) {
    const int e = tid >> 2, q = tid & 3;
    union { uint4 u[2]; __hip_bfloat16 h[16]; } pk;
    if (f) {
        pk.u[0] = *(const uint4*)((const __hip_bfloat16*)Praw + e * 64 + q * 16);
        pk.u[1] = *(const uint4*)((const __hip_bfloat16*)Praw + e * 64 + q * 16 + 8);
    } else {
        const float* ps = (const float*)Praw + e * 64 + q * 16;
#pragma unroll
        for (int j = 0; j < 16; ++j) pk.h[j] = __float2bfloat16(ps[j]);
    }
    *(uint4*)&sP[e * 72 + q * 16]     = pk.u[0];
    *(uint4*)&sP[e * 72 + q * 16 + 8] = pk.u[1];
}

__device__ __forceinline__ float sumsq16(uint4 a, uint4 b) {
    union { uint4 u; __hip_bfloat16 h[8]; } x0, x1;
    x0.u = a; x1.u = b;
    float ss = 0.f;
#pragma unroll
    for (int j = 0; j < 8; ++j) {
        float v0 = __bfloat162float(x0.h[j]); ss += v0 * v0;
        float v1 = __bfloat162float(x1.h[j]); ss += v1 * v1;
    }
    return ss;
}

// ----------------------------- kv kernel -----------------------------------
// grid (16, 64): 256 tokens per block, 4 iters. Partial kv -> private slab
// (plain stores, no atomics). Slab layout: PKV[(slab*64 + bh)*8192 + e*64+d].
__global__ __launch_bounds__(256) void kv_kernel(
    const __hip_bfloat16* __restrict__ Km,
    const __hip_bfloat16* __restrict__ Vm,
    const void* __restrict__ Praw,
    float* __restrict__ PKV,
    const int* __restrict__ flag)
{
    __shared__ __hip_bfloat16 sK[64 * 72];     // [n][d] (wave-local rows)
    __shared__ __hip_bfloat16 sVT[64 * 72];    // [d][n] (cross-wave)
    __shared__ __hip_bfloat16 sP[64 * 72];     // [e][d] (read-only)
    __shared__ __hip_bfloat16 sKFT[128 * 72];  // [e][n] (cross-wave)
    __shared__ float sRN[64];

    const int tid  = threadIdx.x;
    const int lane = tid & 63;
    const int w    = tid >> 6;
    const int lr   = lane & 15, lk = lane >> 4;
    const int bh   = blockIdx.y;
    const int b    = bh >> 4, h = bh & 15;
    const int nst  = blockIdx.x * 256;
    const int f    = *flag;
    const int n    = tid >> 2, q2 = tid & 3;

    load_P(Praw, f, sP, tid);

    f32x4 acck[2][4];
#pragma unroll
    for (int i = 0; i < 2; ++i)
#pragma unroll
        for (int j = 0; j < 4; ++j)
            acck[i][j] = (f32x4){0.f, 0.f, 0.f, 0.f};

    size_t base = ((size_t)(b * 4096 + nst + n)) * 1024 + h * 64 + q2 * 16;
    uint4 ka = *(const uint4*)(Km + base), kb = *(const uint4*)(Km + base + 8);
    uint4 va = *(const uint4*)(Vm + base), vb = *(const uint4*)(Vm + base + 8);

    for (int s = 0; s < 4; ++s) {
        __syncthreads();  // prev kv-MFMA done with sVT/sKFT (s==0: sP visible)
        *(uint4*)&sK[n * 72 + q2 * 16]     = ka;
        *(uint4*)&sK[n * 72 + q2 * 16 + 8] = kb;
        {
            union { uint4 u[2]; __hip_bfloat16 h[16]; } vv;
            vv.u[0] = va; vv.u[1] = vb;
#pragma unroll
            for (int j = 0; j < 16; ++j) sVT[(q2 * 16 + j) * 72 + n] = vv.h[j];
        }
        {
            float ss = sumsq16(ka, kb);
            ss += __shfl_xor(ss, 1, 64);
            ss += __shfl_xor(ss, 2, 64);
            if (q2 == 0) sRN[n] = 2.0f / (sqrtf(ss) + 1e-4f);  // H^0.25 = 2
        }
        if (s < 3) {
            base = ((size_t)(b * 4096 + nst + (s + 1) * 64 + n)) * 1024 + h * 64 + q2 * 16;
            ka = *(const uint4*)(Km + base); kb = *(const uint4*)(Km + base + 8);
            va = *(const uint4*)(Vm + base); vb = *(const uint4*)(Vm + base + 8);
        }
        // proj (wave-local) + sincos -> sKFT
        {
            bf16x8 afr0 = *(const bf16x8*)&sK[(w * 16 + lr) * 72 + lk * 8];
            bf16x8 afr1 = *(const bf16x8*)&sK[(w * 16 + lr) * 72 + 32 + lk * 8];
            float rn[4];
#pragma unroll
            for (int r = 0; r < 4; ++r) rn[r] = sRN[w * 16 + lk * 4 + r];
#pragma unroll
            for (int eb = 0; eb < 4; ++eb) {
                f32x4 pa = (f32x4){0.f, 0.f, 0.f, 0.f};
                bf16x8 b0 = *(const bf16x8*)&sP[(eb * 16 + lr) * 72 + lk * 8];
                bf16x8 b1 = *(const bf16x8*)&sP[(eb * 16 + lr) * 72 + 32 + lk * 8];
                pa = __builtin_amdgcn_mfma_f32_16x16x32_bf16(afr0, b0, pa, 0, 0, 0);
                pa = __builtin_amdgcn_mfma_f32_16x16x32_bf16(afr1, b1, pa, 0, 0, 0);
                const int col = eb * 16 + lr;
#pragma unroll
                for (int r = 0; r < 4; ++r) {
                    const int row = w * 16 + lk * 4 + r;
                    float sv, cv;
                    __sincosf(pa[r] * rn[r], &sv, &cv);
                    sKFT[col * 72 + row]        = __float2bfloat16(sv * 0.125f);
                    sKFT[(col + 64) * 72 + row] = __float2bfloat16(cv * 0.125f);
                }
            }
        }
        __syncthreads();  // sKFT + sVT complete across waves
#pragma unroll
        for (int ks = 0; ks < 2; ++ks) {
            bf16x8 a2[2], b2[4];
            a2[0] = *(const bf16x8*)&sKFT[(w * 16 + lr) * 72 + ks * 32 + lk * 8];
            a2[1] = *(const bf16x8*)&sKFT[((w + 4) * 16 + lr) * 72 + ks * 32 + lk * 8];
#pragma unroll
            for (int db = 0; db < 4; ++db)
                b2[db] = *(const bf16x8*)&sVT[(db * 16 + lr) * 72 + ks * 32 + lk * 8];
#pragma unroll
            for (int i = 0; i < 2; ++i)
#pragma unroll
                for (int db = 0; db < 4; ++db)
                    acck[i][db] = __builtin_amdgcn_mfma_f32_16x16x32_bf16(
                        a2[i], b2[db], acck[i][db], 0, 0, 0);
        }
    }

    float* out = PKV + ((size_t)blockIdx.x * 64 + bh) * 8192;
#pragma unroll
    for (int i = 0; i < 2; ++i)
#pragma unroll
        for (int db = 0; db < 4; ++db)
#pragma unroll
            for (int r = 0; r < 4; ++r) {
                const int e = (w + 4 * i) * 16 + lk * 4 + r;
                const int d = db * 16 + lr;
                out[e * 64 + d] = acck[i][db][r];
            }
}

// --------------------------- kv reduce kernel ------------------------------
__global__ __launch_bounds__(256) void kv_reduce_kernel(
    const float* __restrict__ PKV, float* __restrict__ gKV)
{
    const int i = (blockIdx.x * 256 + threadIdx.x) * 4;
    f32x4 s = (f32x4){0.f, 0.f, 0.f, 0.f};
#pragma unroll
    for (int sl = 0; sl < KV_SLABS; ++sl) {
        const float4 v = *(const float4*)(PKV + (size_t)sl * 64 * 8192 + i);
        s[0] += v.x; s[1] += v.y; s[2] += v.z; s[3] += v.w;
    }
    *(float4*)(gKV + i) = *(float4*)&s;
}

// ----------------------------- o kernel ------------------------------------
__global__ __launch_bounds__(256) void o_kernel(
    const __hip_bfloat16* __restrict__ Qm,
    const void* __restrict__ Praw,
    const float* __restrict__ gKV,
    __hip_bfloat16* __restrict__ O,
    const int* __restrict__ flag)
{
    __shared__ __hip_bfloat16 sQ[64 * 72];     // [n][d] wave-local rows
    __shared__ __hip_bfloat16 sP[64 * 72];     // read-only
    __shared__ __hip_bfloat16 sQF[64 * 136];   // [n][e] wave-local rows
    __shared__ __hip_bfloat16 sKVT[64 * 136];  // [d][e] read-only
    __shared__ float sRN[64];

    const int tid  = threadIdx.x;
    const int lane = tid & 63;
    const int w    = tid >> 6;
    const int lr   = lane & 15, lk = lane >> 4;
    const int bh   = blockIdx.y;
    const int b    = bh >> 4, h = bh & 15;
    const int nst  = blockIdx.x * 256;
    const int f    = *flag;
    const int n    = tid >> 2, q2 = tid & 3;

    load_P(Praw, f, sP, tid);
    {
        const float* kvsrc = gKV + (size_t)bh * 8192;
        for (int t = tid; t < 8192; t += 256) {
            const int e = t >> 6, d = t & 63;
            sKVT[d * 136 + e] = __float2bfloat16(kvsrc[t]);
        }
    }

    size_t base = ((size_t)(b * 4096 + nst + n)) * 1024 + h * 64 + q2 * 16;
    uint4 qa = *(const uint4*)(Qm + base), qb = *(const uint4*)(Qm + base + 8);

    __syncthreads();  // sP + sKVT visible to all waves

    for (int s = 0; s < 4; ++s) {
        const int gn0 = nst + s * 64;
        *(uint4*)&sQ[n * 72 + q2 * 16]     = qa;
        *(uint4*)&sQ[n * 72 + q2 * 16 + 8] = qb;
        {
            float ss = sumsq16(qa, qb);
            ss += __shfl_xor(ss, 1, 64);
            ss += __shfl_xor(ss, 2, 64);
            if (q2 == 0) sRN[n] = 2.0f / (sqrtf(ss) + 1e-4f);
        }
        if (s < 3) {
            base = ((size_t)(b * 4096 + nst + (s + 1) * 64 + n)) * 1024 + h * 64 + q2 * 16;
            qa = *(const uint4*)(Qm + base); qb = *(const uint4*)(Qm + base + 8);
        }
        {
            bf16x8 afr0 = *(const bf16x8*)&sQ[(w * 16 + lr) * 72 + lk * 8];
            bf16x8 afr1 = *(const bf16x8*)&sQ[(w * 16 + lr) * 72 + 32 + lk * 8];
            float rn[4];
#pragma unroll
            for (int r = 0; r < 4; ++r) rn[r] = sRN[w * 16 + lk * 4 + r];
#pragma unroll
            for (int eb = 0; eb < 4; ++eb) {
                f32x4 pa = (f32x4){0.f, 0.f, 0.f, 0.f};
                bf16x8 b0 = *(const bf16x8*)&sP[(eb * 16 + lr) * 72 + lk * 8];
                bf16x8 b1 = *(const bf16x8*)&sP[(eb * 16 + lr) * 72 + 32 + lk * 8];
                pa = __builtin_amdgcn_mfma_f32_16x16x32_bf16(afr0, b0, pa, 0, 0, 0);
                pa = __builtin_amdgcn_mfma_f32_16x16x32_bf16(afr1, b1, pa, 0, 0, 0);
                const int col = eb * 16 + lr;
#pragma unroll
                for (int r = 0; r < 4; ++r) {
                    const int row = w * 16 + lk * 4 + r;
                    float sv, cv;
                    __sincosf(pa[r] * rn[r], &sv, &cv);
                    sQF[row * 136 + col]      = __float2bfloat16(sv * 0.125f);
                    sQF[row * 136 + 64 + col] = __float2bfloat16(cv * 0.125f);
                }
            }
        }
        f32x4 oacc[4];
#pragma unroll
        for (int nb = 0; nb < 4; ++nb) oacc[nb] = (f32x4){0.f, 0.f, 0.f, 0.f};
#pragma unroll
        for (int ks = 0; ks < 4; ++ks) {
            bf16x8 aa = *(const bf16x8*)&sQF[(w * 16 + lr) * 136 + ks * 32 + lk * 8];
#pragma unroll
            for (int nb = 0; nb < 4; ++nb) {
                bf16x8 bb = *(const bf16x8*)&sKVT[(nb * 16 + lr) * 136 + ks * 32 + lk * 8];
                oacc[nb] = __builtin_amdgcn_mfma_f32_16x16x32_bf16(aa, bb, oacc[nb], 0, 0, 0);
            }
        }
#pragma unroll
        for (int nb = 0; nb < 4; ++nb)
#pragma unroll
            for (int r = 0; r < 4; ++r)
                sQ[(w * 16 + lk * 4 + r) * 72 + nb * 16 + lr] =
                    __float2bfloat16(oacc[nb][r]);
        {
            uint4 o0 = *(uint4*)&sQ[n * 72 + q2 * 16];
            uint4 o1 = *(uint4*)&sQ[n * 72 + q2 * 16 + 8];
            const size_t obase = ((size_t)(b * 4096 + gn0 + n)) * 1024 + h * 64 + q2 * 16;
            *(uint4*)(O + obase)     = o0;
            *(uint4*)(O + obase + 8) = o1;
        }
    }
}

// ----------------------------- launcher ------------------------------------
extern "C" void kernel_launch(void* const* d_in, const int* in_sizes, int n_in,
                              void* d_out, int out_size, void* d_ws, size_t ws_size,
                              hipStream_t stream)
{
    (void)in_sizes; (void)n_in; (void)out_size; (void)ws_size;
    const void* x  = d_in[0];
    const void* Wq = d_in[1];
    const void* bq = d_in[2];
    const void* Wk = d_in[3];
    const void* bk = d_in[4];
    const void* Wv = d_in[5];
    const void* bv = d_in[6];
    const void* Wo = d_in[7];
    const void* bo = d_in[8];
    const void* P  = d_in[9];

    constexpr size_t XE = (size_t)GM * GN;
    constexpr size_t WE = (size_t)GN * GK;
    constexpr size_t KVE = (size_t)64 * 128 * 64;

    __hip_bfloat16* xb  = (__hip_bfloat16*)d_ws;
    __hip_bfloat16* wqb = xb + XE;
    __hip_bfloat16* wkb = wqb + WE;
    __hip_bfloat16* wvb = wkb + WE;
    __hip_bfloat16* wob = wvb + WE;
    __hip_bfloat16* R1  = wob + WE;          // K, later O
    __hip_bfloat16* R2  = R1 + XE;           // V, later Q
    float* gKV = (float*)(R2 + XE);
    float* PKV = gKV + KVE;                  // 16 slabs x 64 x 8192
    int* flag  = (int*)(PKV + (size_t)KV_SLABS * 64 * 8192);

    dim3 blk(256);
    hipLaunchKernelGGL(detect_kernel, dim3(1), dim3(64), 0, stream,
                       (const unsigned short*)x, flag);

    hipLaunchKernelGGL(cvt_kernel, dim3(8192), blk, 0, stream, x, xb, (int)XE, flag);
    hipLaunchKernelGGL(cvt4_kernel, dim3(2048), blk, 0, stream,
                       Wq, wqb, Wk, wkb, Wv, wvb, Wo, wob, flag);

    // K, V (2-out, shared A)
    hipLaunchKernelGGL(gemm2_kernel, dim3(1024), blk, 0, stream,
                       x, xb, Wk, wkb, Wv, wvb, bk, bv, R1, R2, flag);
    hipLaunchKernelGGL(kv_kernel, dim3(KV_SLABS, 64), blk, 0, stream, R1, R2, P, PKV, flag);
    hipLaunchKernelGGL(kv_reduce_kernel, dim3(512), blk, 0, stream, PKV, gKV);
    // Q (V dead -> R2), dual-M
    hipLaunchKernelGGL(gemm1m2_kernel, dim3(512), blk, 0, stream,
                       x, xb, Wq, wqb, bq, R2, flag, 0);
    hipLaunchKernelGGL(o_kernel, dim3(16, 64), blk, 0, stream, R2, P, gKV, R1, flag);
    // out = O@Wo^T + bo, dual-M
    hipLaunchKernelGGL(gemm1m2_kernel, dim3(512), blk, 0, stream,
                       R1, R1, Wo, wob, bo, d_out, flag, 1);
}